// Round 1
// baseline (363.152 us; speedup 1.0000x reference)
//
#include <hip/hip_runtime.h>
#include <math.h>

#define N_NODES 50000
#define E_EDGES 800000
#define IN_DIM  128
#define HD      128   // H*D
#define SQRT_D_INV 0.25f

// ---------------- projection GEMM: O[n,c] = sum_k A[n,k]*W[k,c] + b[c] ----------------
// blockIdx.y: 0 -> Q (A=h_dst), 1 -> K (A=h_src), 2 -> V (A=h_src)
__global__ __launch_bounds__(256) void proj_kernel(
    const float* __restrict__ h_src, const float* __restrict__ h_dst,
    const float* __restrict__ Qw, const float* __restrict__ Qb,
    const float* __restrict__ Kw, const float* __restrict__ Kb,
    const float* __restrict__ Vw, const float* __restrict__ Vb,
    float* __restrict__ Qo, float* __restrict__ Ko, float* __restrict__ Vo)
{
    const int which = blockIdx.y;
    const float* A = (which == 0) ? h_dst : h_src;
    const float* W = (which == 0) ? Qw : (which == 1) ? Kw : Vw;
    const float* b = (which == 0) ? Qb : (which == 1) ? Kb : Vb;
    float* O       = (which == 0) ? Qo : (which == 1) ? Ko : Vo;

    __shared__ float As[64][IN_DIM];
    const int n0 = blockIdx.x * 64;
    const int t  = threadIdx.x;

    // cooperative A-tile load: 64x128 floats, float4 per thread x 8
    #pragma unroll
    for (int r = 0; r < 8; ++r) {
        int idx = r * 1024 + t * 4;
        int n = idx >> 7, k = idx & 127;
        float4 v = make_float4(0.f, 0.f, 0.f, 0.f);
        if (n0 + n < N_NODES) v = *(const float4*)&A[(size_t)(n0 + n) * IN_DIM + k];
        *(float4*)&As[n][k] = v;
    }
    __syncthreads();

    const int cg = t & 31;   // 32 col-groups * 4 cols = 128 cols
    const int ng = t >> 5;   // 8 node-groups * 8 nodes = 64 nodes

    float acc[8][4];
    #pragma unroll
    for (int i = 0; i < 8; ++i)
        #pragma unroll
        for (int j = 0; j < 4; ++j) acc[i][j] = 0.f;

    for (int k = 0; k < IN_DIM; k += 4) {
        float4 w0 = *(const float4*)&W[(k + 0) * HD + cg * 4];
        float4 w1 = *(const float4*)&W[(k + 1) * HD + cg * 4];
        float4 w2 = *(const float4*)&W[(k + 2) * HD + cg * 4];
        float4 w3 = *(const float4*)&W[(k + 3) * HD + cg * 4];
        #pragma unroll
        for (int i = 0; i < 8; ++i) {
            float4 a = *(const float4*)&As[ng * 8 + i][k];
            acc[i][0] += a.x * w0.x + a.y * w1.x + a.z * w2.x + a.w * w3.x;
            acc[i][1] += a.x * w0.y + a.y * w1.y + a.z * w2.y + a.w * w3.y;
            acc[i][2] += a.x * w0.z + a.y * w1.z + a.z * w2.z + a.w * w3.z;
            acc[i][3] += a.x * w0.w + a.y * w1.w + a.z * w2.w + a.w * w3.w;
        }
    }

    float4 bias = *(const float4*)&b[cg * 4];
    #pragma unroll
    for (int i = 0; i < 8; ++i) {
        int n = n0 + ng * 8 + i;
        if (n < N_NODES) {
            float4 o = make_float4(acc[i][0] + bias.x, acc[i][1] + bias.y,
                                   acc[i][2] + bias.z, acc[i][3] + bias.w);
            *(float4*)&O[(size_t)n * HD + cg * 4] = o;
        }
    }
}

// ---------------- CSR build ----------------
__global__ void hist_kernel(const int* __restrict__ dst, int* __restrict__ counts) {
    int e = blockIdx.x * blockDim.x + threadIdx.x;
    if (e < E_EDGES) atomicAdd(&counts[dst[e]], 1);
}

__global__ __launch_bounds__(1024) void scan_kernel(const int* __restrict__ counts,
                                                    int* __restrict__ rowptr,
                                                    int* __restrict__ next) {
    __shared__ int sh[1024];
    const int t = threadIdx.x;
    int carry = 0;
    for (int base = 0; base < N_NODES; base += 1024) {
        int i = base + t;
        int v = (i < N_NODES) ? counts[i] : 0;
        __syncthreads();            // protect sh[] from previous chunk's readers
        sh[t] = v;
        __syncthreads();
        for (int off = 1; off < 1024; off <<= 1) {
            int y = (t >= off) ? sh[t - off] : 0;
            __syncthreads();
            sh[t] += y;
            __syncthreads();
        }
        int incl  = sh[t];
        int total = sh[1023];
        int excl  = incl - v + carry;
        if (i < N_NODES) { rowptr[i] = excl; next[i] = excl; }
        carry += total;
    }
    if (t == 0) rowptr[N_NODES] = carry;  // == E_EDGES
}

__global__ void scatter_kernel(const int* __restrict__ src, const int* __restrict__ dst,
                               int* __restrict__ next, int* __restrict__ esrc) {
    int e = blockIdx.x * blockDim.x + threadIdx.x;
    if (e < E_EDGES) {
        int p = atomicAdd(&next[dst[e]], 1);
        esrc[p] = src[e];
    }
}

// ---------------- aggregation: one wave (64 lanes) per destination node ----------------
// lane l owns channels 2l, 2l+1 ; head = l>>3 ; 8 lanes per head, shfl_xor(1,2,4) reduces head dot
__global__ __launch_bounds__(256) void agg_kernel(
    const float* __restrict__ Q, const float* __restrict__ K, const float* __restrict__ V,
    const int* __restrict__ rowptr, const int* __restrict__ esrc,
    float* __restrict__ out)
{
    const int wave = (blockIdx.x * blockDim.x + threadIdx.x) >> 6;
    const int lane = threadIdx.x & 63;
    if (wave >= N_NODES) return;
    const int n = wave;

    float2 q = *(const float2*)&Q[(size_t)n * HD + lane * 2];
    const int beg = rowptr[n], end = rowptr[n + 1];

    float2 acc = make_float2(0.f, 0.f);
    float zsum = 0.f;

    int i = beg;
    int s = (i < end) ? esrc[i] : 0;
    for (; i < end; ++i) {
        float2 k2 = *(const float2*)&K[(size_t)s * HD + lane * 2];
        float2 v2 = *(const float2*)&V[(size_t)s * HD + lane * 2];
        int s_next = (i + 1 < end) ? esrc[i + 1] : 0;   // prefetch next index
        float d = q.x * k2.x + q.y * k2.y;
        d += __shfl_xor(d, 1);
        d += __shfl_xor(d, 2);
        d += __shfl_xor(d, 4);
        float sc = __expf(fminf(fmaxf(d * SQRT_D_INV, -5.f), 5.f));
        acc.x += sc * v2.x;
        acc.y += sc * v2.y;
        zsum  += sc;
        s = s_next;
    }

    float inv = 1.f / zsum;   // deg==0 -> 0*inf = NaN, matching reference 0/0
    float2 o = make_float2(acc.x * inv, acc.y * inv);
    *(float2*)&out[(size_t)n * HD + lane * 2] = o;
}

// ---------------- launcher ----------------
extern "C" void kernel_launch(void* const* d_in, const int* in_sizes, int n_in,
                              void* d_out, int out_size, void* d_ws, size_t ws_size,
                              hipStream_t stream) {
    const float* h_src = (const float*)d_in[0];
    const float* h_dst = (const float*)d_in[1];
    const int*   src   = (const int*)d_in[2];
    const int*   dst   = (const int*)d_in[3];
    const float* Qw    = (const float*)d_in[4];
    const float* Qb    = (const float*)d_in[5];
    const float* Kw    = (const float*)d_in[6];
    const float* Kb    = (const float*)d_in[7];
    const float* Vw    = (const float*)d_in[8];
    const float* Vb    = (const float*)d_in[9];
    float* out = (float*)d_out;

    char* ws = (char*)d_ws;
    const size_t qkv_bytes = (size_t)N_NODES * HD * sizeof(float);   // 25.6 MB each
    float* Qp    = (float*)(ws);
    float* Kp    = (float*)(ws + qkv_bytes);
    float* Vp    = (float*)(ws + 2 * qkv_bytes);
    int* counts  = (int*)(ws + 3 * qkv_bytes);
    int* rowptr  = counts + N_NODES;           // N+1 entries
    int* next    = rowptr + N_NODES + 1;
    int* esrc    = next + N_NODES;

    hipMemsetAsync(counts, 0, N_NODES * sizeof(int), stream);

    dim3 pgrid((N_NODES + 63) / 64, 3);
    proj_kernel<<<pgrid, 256, 0, stream>>>(h_src, h_dst, Qw, Qb, Kw, Kb, Vw, Vb, Qp, Kp, Vp);

    hist_kernel<<<(E_EDGES + 255) / 256, 256, 0, stream>>>(dst, counts);
    scan_kernel<<<1, 1024, 0, stream>>>(counts, rowptr, next);
    scatter_kernel<<<(E_EDGES + 255) / 256, 256, 0, stream>>>(src, dst, next, esrc);

    agg_kernel<<<(N_NODES * 64 + 255) / 256, 256, 0, stream>>>(Qp, Kp, Vp, rowptr, esrc, out);
}

// Round 2
// 251.225 us; speedup vs baseline: 1.4455x; 1.4455x over previous
//
#include <hip/hip_runtime.h>
#include <hip/hip_bf16.h>
#include <math.h>

#define N_NODES 50000
#define E_EDGES 800000
#define IN_DIM  128
#define HD      128   // H*D
#define SQRT_D_INV 0.25f

__device__ inline unsigned short f2bf(float x) {
    __hip_bfloat16 b = __float2bfloat16(x);
    return *reinterpret_cast<unsigned short*>(&b);
}
__device__ inline float bflo(unsigned int u) { return __uint_as_float(u << 16); }
__device__ inline float bfhi(unsigned int u) { return __uint_as_float(u & 0xffff0000u); }

// ---------------- projection GEMM: O[n,c] = sum_k A[n,k]*W[k,c] + b[c] ----------------
// blockIdx.y: 0 -> Q (A=h_dst, fp32 out), 1 -> K (A=h_src, bf16 into kv[:,0:128]),
//             2 -> V (A=h_src, bf16 into kv[:,128:256])
__global__ __launch_bounds__(256) void proj_kernel(
    const float* __restrict__ h_src, const float* __restrict__ h_dst,
    const float* __restrict__ Qw, const float* __restrict__ Qb,
    const float* __restrict__ Kw, const float* __restrict__ Kb,
    const float* __restrict__ Vw, const float* __restrict__ Vb,
    float* __restrict__ Qo, unsigned short* __restrict__ kv)
{
    const int which = blockIdx.y;
    const float* A = (which == 0) ? h_dst : h_src;
    const float* W = (which == 0) ? Qw : (which == 1) ? Kw : Vw;
    const float* b = (which == 0) ? Qb : (which == 1) ? Kb : Vb;

    __shared__ float As[64][IN_DIM];
    const int n0 = blockIdx.x * 64;
    const int t  = threadIdx.x;

    #pragma unroll
    for (int r = 0; r < 8; ++r) {
        int idx = r * 1024 + t * 4;
        int n = idx >> 7, k = idx & 127;
        float4 v = make_float4(0.f, 0.f, 0.f, 0.f);
        if (n0 + n < N_NODES) v = *(const float4*)&A[(size_t)(n0 + n) * IN_DIM + k];
        *(float4*)&As[n][k] = v;
    }
    __syncthreads();

    const int cg = t & 31;   // 32 col-groups * 4 cols
    const int ng = t >> 5;   // 8 node-groups * 8 nodes

    float acc[8][4];
    #pragma unroll
    for (int i = 0; i < 8; ++i)
        #pragma unroll
        for (int j = 0; j < 4; ++j) acc[i][j] = 0.f;

    for (int k = 0; k < IN_DIM; k += 4) {
        float4 w0 = *(const float4*)&W[(k + 0) * HD + cg * 4];
        float4 w1 = *(const float4*)&W[(k + 1) * HD + cg * 4];
        float4 w2 = *(const float4*)&W[(k + 2) * HD + cg * 4];
        float4 w3 = *(const float4*)&W[(k + 3) * HD + cg * 4];
        #pragma unroll
        for (int i = 0; i < 8; ++i) {
            float4 a = *(const float4*)&As[ng * 8 + i][k];
            acc[i][0] += a.x * w0.x + a.y * w1.x + a.z * w2.x + a.w * w3.x;
            acc[i][1] += a.x * w0.y + a.y * w1.y + a.z * w2.y + a.w * w3.y;
            acc[i][2] += a.x * w0.z + a.y * w1.z + a.z * w2.z + a.w * w3.z;
            acc[i][3] += a.x * w0.w + a.y * w1.w + a.z * w2.w + a.w * w3.w;
        }
    }

    float4 bias = *(const float4*)&b[cg * 4];
    #pragma unroll
    for (int i = 0; i < 8; ++i) {
        int n = n0 + ng * 8 + i;
        if (n >= N_NODES) continue;
        float o0 = acc[i][0] + bias.x, o1 = acc[i][1] + bias.y;
        float o2 = acc[i][2] + bias.z, o3 = acc[i][3] + bias.w;
        if (which == 0) {
            *(float4*)&Qo[(size_t)n * HD + cg * 4] = make_float4(o0, o1, o2, o3);
        } else {
            ushort4 u;
            u.x = f2bf(o0); u.y = f2bf(o1); u.z = f2bf(o2); u.w = f2bf(o3);
            int off = (which == 1) ? 0 : HD;
            *(ushort4*)&kv[(size_t)n * 2 * HD + off + cg * 4] = u;
        }
    }
}

// ---------------- CSR build ----------------
__global__ void hist_kernel(const int* __restrict__ dst, int* __restrict__ counts) {
    int e = blockIdx.x * blockDim.x + threadIdx.x;
    if (e < E_EDGES) atomicAdd(&counts[dst[e]], 1);
}

// wave-level prefix scan + one atomic per wave -> beg[], next[]
__global__ __launch_bounds__(256) void offsets_kernel(const int* __restrict__ counts,
                                                      int* __restrict__ beg,
                                                      int* __restrict__ next,
                                                      int* __restrict__ total) {
    int i = blockIdx.x * blockDim.x + threadIdx.x;
    int lane = threadIdx.x & 63;
    int v = (i < N_NODES) ? counts[i] : 0;
    int incl = v;
    #pragma unroll
    for (int off = 1; off < 64; off <<= 1) {
        int y = __shfl_up(incl, off);
        if (lane >= off) incl += y;
    }
    int wsum = __shfl(incl, 63);
    int base = 0;
    if (lane == 0) base = atomicAdd(total, wsum);
    base = __shfl(base, 0);
    int b = base + incl - v;
    if (i < N_NODES) { beg[i] = b; next[i] = b; }
}

__global__ void scatter_kernel(const int* __restrict__ src, const int* __restrict__ dst,
                               int* __restrict__ next, int* __restrict__ esrc) {
    int e = blockIdx.x * blockDim.x + threadIdx.x;
    if (e < E_EDGES) {
        int p = atomicAdd(&next[dst[e]], 1);
        esrc[p] = src[e];
    }
}

// ---------------- aggregation: one wave per destination node, bf16 KV, 4-edge batches ----
__global__ __launch_bounds__(256) void agg_kernel(
    const float* __restrict__ Q, const unsigned int* __restrict__ kv,
    const int* __restrict__ begp, const int* __restrict__ cntp,
    const int* __restrict__ esrc, float* __restrict__ out)
{
    const int wave = (blockIdx.x * blockDim.x + threadIdx.x) >> 6;
    const int lane = threadIdx.x & 63;
    if (wave >= N_NODES) return;
    const int n = wave;

    float2 q = *(const float2*)&Q[(size_t)n * HD + lane * 2];
    const int beg = begp[n], cnt = cntp[n], end = beg + cnt;

    float2 acc = make_float2(0.f, 0.f);
    float zsum = 0.f;

    for (int i = beg; i < end; i += 4) {
        const int m = end - i;       // >= 1, wave-uniform
        int s0 = esrc[i];
        int s1 = (m > 1) ? esrc[i + 1] : s0;
        int s2 = (m > 2) ? esrc[i + 2] : s0;
        int s3 = (m > 3) ? esrc[i + 3] : s0;
        // 8 coalesced 256B row-segment loads in flight
        unsigned int k0 = kv[(size_t)s0 * 128 + lane];
        unsigned int v0 = kv[(size_t)s0 * 128 + 64 + lane];
        unsigned int k1 = kv[(size_t)s1 * 128 + lane];
        unsigned int v1 = kv[(size_t)s1 * 128 + 64 + lane];
        unsigned int k2 = kv[(size_t)s2 * 128 + lane];
        unsigned int v2 = kv[(size_t)s2 * 128 + 64 + lane];
        unsigned int k3 = kv[(size_t)s3 * 128 + lane];
        unsigned int v3 = kv[(size_t)s3 * 128 + 64 + lane];

        unsigned int ks[4] = {k0, k1, k2, k3};
        unsigned int vs[4] = {v0, v1, v2, v3};
        #pragma unroll
        for (int j = 0; j < 4; ++j) {
            float d = q.x * bflo(ks[j]) + q.y * bfhi(ks[j]);
            d += __shfl_xor(d, 1);
            d += __shfl_xor(d, 2);
            d += __shfl_xor(d, 4);
            float sc = __expf(fminf(fmaxf(d * SQRT_D_INV, -5.f), 5.f));
            float w = (j < m) ? sc : 0.f;
            acc.x += w * bflo(vs[j]);
            acc.y += w * bfhi(vs[j]);
            zsum  += w;
        }
    }

    float inv = 1.f / zsum;
    *(float2*)&out[(size_t)n * HD + lane * 2] = make_float2(acc.x * inv, acc.y * inv);
}

// ---------------- launcher ----------------
extern "C" void kernel_launch(void* const* d_in, const int* in_sizes, int n_in,
                              void* d_out, int out_size, void* d_ws, size_t ws_size,
                              hipStream_t stream) {
    const float* h_src = (const float*)d_in[0];
    const float* h_dst = (const float*)d_in[1];
    const int*   src   = (const int*)d_in[2];
    const int*   dst   = (const int*)d_in[3];
    const float* Qw    = (const float*)d_in[4];
    const float* Qb    = (const float*)d_in[5];
    const float* Kw    = (const float*)d_in[6];
    const float* Kb    = (const float*)d_in[7];
    const float* Vw    = (const float*)d_in[8];
    const float* Vb    = (const float*)d_in[9];
    float* out = (float*)d_out;

    char* ws = (char*)d_ws;
    const size_t q_bytes  = (size_t)N_NODES * HD * sizeof(float);          // 25.6 MB
    const size_t kv_bytes = (size_t)N_NODES * 2 * HD * sizeof(unsigned short); // 25.6 MB
    float*          Qp   = (float*)(ws);
    unsigned short* kvp  = (unsigned short*)(ws + q_bytes);
    int* counts = (int*)(ws + q_bytes + kv_bytes);
    int* total  = counts + N_NODES;            // 1 int, memset together with counts
    int* beg    = total + 1;
    int* next   = beg + N_NODES;
    int* esrc   = next + N_NODES;

    hipMemsetAsync(counts, 0, (N_NODES + 1) * sizeof(int), stream);

    dim3 pgrid((N_NODES + 63) / 64, 3);
    proj_kernel<<<pgrid, 256, 0, stream>>>(h_src, h_dst, Qw, Qb, Kw, Kb, Vw, Vb, Qp, kvp);

    hist_kernel<<<(E_EDGES + 255) / 256, 256, 0, stream>>>(dst, counts);
    offsets_kernel<<<(N_NODES + 255) / 256, 256, 0, stream>>>(counts, beg, next, total);
    scatter_kernel<<<(E_EDGES + 255) / 256, 256, 0, stream>>>(src, dst, next, esrc);

    agg_kernel<<<(N_NODES * 64 + 255) / 256, 256, 0, stream>>>(Qp, (const unsigned int*)kvp,
                                                               beg, counts, esrc, out);
}

// Round 3
// 228.913 us; speedup vs baseline: 1.5864x; 1.0975x over previous
//
#include <hip/hip_runtime.h>
#include <hip/hip_bf16.h>
#include <math.h>

#define N_NODES 50000
#define E_EDGES 800000
#define IN_DIM  128
#define HD      128   // H*D
#define SQRT_D_INV 0.25f

typedef __attribute__((ext_vector_type(8))) short short8v;
typedef __attribute__((ext_vector_type(4))) float float4v;

__device__ inline unsigned short f2bf(float x) {
    __hip_bfloat16 b = __float2bfloat16(x);
    return *reinterpret_cast<unsigned short*>(&b);
}
__device__ inline float bflo(unsigned int u) { return __uint_as_float(u << 16); }
__device__ inline float bfhi(unsigned int u) { return __uint_as_float(u & 0xffff0000u); }

// ---------------- W transpose+convert: wt[which][n][k] = bf16(W[k][n]) ----------------
__global__ __launch_bounds__(256) void wtr_kernel(
    const float* __restrict__ Qw, const float* __restrict__ Kw, const float* __restrict__ Vw,
    unsigned short* __restrict__ wt)
{
    int i = blockIdx.x * 256 + threadIdx.x;          // 3*16384 total
    int which = i >> 14;
    int r = i & 16383;                               // r = k*128 + n
    int k = r >> 7, n = r & 127;
    const float* W = (which == 0) ? Qw : (which == 1) ? Kw : Vw;
    wt[((size_t)which << 14) + n * 128 + k] = f2bf(W[r]);
}

// ---------------- MFMA projection ----------------
// block: 256 thr = 4 waves, 64 rows/block (16 rows/wave), full 128 cols.
// blockIdx.y: 0 -> Q (fp32 out), 1 -> K (bf16 kv[:,0:128]), 2 -> V (bf16 kv[:,128:256])
__global__ __launch_bounds__(256) void proj_mfma_kernel(
    const float* __restrict__ h_src, const float* __restrict__ h_dst,
    const unsigned short* __restrict__ wt,
    const float* __restrict__ Qb, const float* __restrict__ Kb, const float* __restrict__ Vb,
    float* __restrict__ Qo, unsigned short* __restrict__ kv)
{
    const int which = blockIdx.y;
    const float* A = (which == 0) ? h_dst : h_src;
    const float* bias = (which == 0) ? Qb : (which == 1) ? Kb : Vb;
    const unsigned short* W = wt + ((size_t)which << 14);

    const int t  = threadIdx.x;
    const int wv = t >> 6;
    const int l  = t & 63;
    const int lr = l & 15;       // A-row within wave tile / B-col within n-frag
    const int kg = l >> 4;       // k-group 0..3 (8 consecutive k each)
    const int m_base = blockIdx.x * 64 + wv * 16;
    const int arow = m_base + lr;
    const bool rok = arow < N_NODES;
    const float* ap = A + (size_t)(rok ? arow : 0) * IN_DIM;

    float4v acc[8];
    #pragma unroll
    for (int i = 0; i < 8; ++i) acc[i] = (float4v)0.f;

    #pragma unroll
    for (int ks = 0; ks < 4; ++ks) {
        const int k0 = ks * 32 + kg * 8;
        float4 a0 = *(const float4*)&ap[k0];
        float4 a1 = *(const float4*)&ap[k0 + 4];
        short8v af;
        af[0] = (short)f2bf(a0.x); af[1] = (short)f2bf(a0.y);
        af[2] = (short)f2bf(a0.z); af[3] = (short)f2bf(a0.w);
        af[4] = (short)f2bf(a1.x); af[5] = (short)f2bf(a1.y);
        af[6] = (short)f2bf(a1.z); af[7] = (short)f2bf(a1.w);
        #pragma unroll
        for (int nf = 0; nf < 8; ++nf) {
            short8v bf = *(const short8v*)&W[(size_t)(nf * 16 + lr) * 128 + k0];
            acc[nf] = __builtin_amdgcn_mfma_f32_16x16x32_bf16(af, bf, acc[nf], 0, 0, 0);
        }
    }

    // C/D layout: col = lane&15, row = (lane>>4)*4 + reg   [verified m89]
    #pragma unroll
    for (int nf = 0; nf < 8; ++nf) {
        const int col = nf * 16 + lr;
        const float b = bias[col];
        #pragma unroll
        for (int r = 0; r < 4; ++r) {
            const int m = m_base + kg * 4 + r;
            if (m < N_NODES) {
                const float o = acc[nf][r] + b;
                if (which == 0) Qo[(size_t)m * HD + col] = o;
                else kv[(size_t)m * 2 * HD + (which == 1 ? 0 : HD) + col] = f2bf(o);
            }
        }
    }
}

// ---------------- CSR build ----------------
__global__ void hist_kernel(const int* __restrict__ dst, int* __restrict__ counts) {
    int e = blockIdx.x * blockDim.x + threadIdx.x;
    if (e < E_EDGES) atomicAdd(&counts[dst[e]], 1);
}

__global__ __launch_bounds__(256) void offsets_kernel(const int* __restrict__ counts,
                                                      int* __restrict__ beg,
                                                      int* __restrict__ next,
                                                      int* __restrict__ total) {
    int i = blockIdx.x * blockDim.x + threadIdx.x;
    int lane = threadIdx.x & 63;
    int v = (i < N_NODES) ? counts[i] : 0;
    int incl = v;
    #pragma unroll
    for (int off = 1; off < 64; off <<= 1) {
        int y = __shfl_up(incl, off);
        if (lane >= off) incl += y;
    }
    int wsum = __shfl(incl, 63);
    int base = 0;
    if (lane == 0) base = atomicAdd(total, wsum);
    base = __shfl(base, 0);
    int b = base + incl - v;
    if (i < N_NODES) { beg[i] = b; next[i] = b; }
}

__global__ void scatter_kernel(const int* __restrict__ src, const int* __restrict__ dst,
                               int* __restrict__ next, int* __restrict__ esrc) {
    int e = blockIdx.x * blockDim.x + threadIdx.x;
    if (e < E_EDGES) {
        int p = atomicAdd(&next[dst[e]], 1);
        esrc[p] = src[e];
    }
}

// ---------------- aggregation: one wave per node, bf16 KV, 8-edge batches ----------------
__global__ __launch_bounds__(256) void agg_kernel(
    const float* __restrict__ Q, const unsigned int* __restrict__ kv,
    const int* __restrict__ begp, const int* __restrict__ cntp,
    const int* __restrict__ esrc, float* __restrict__ out)
{
    int wave = (blockIdx.x * blockDim.x + threadIdx.x) >> 6;
    const int lane = threadIdx.x & 63;
    if (wave >= N_NODES) return;
    const int n = __builtin_amdgcn_readfirstlane(wave);   // wave-uniform -> s_loads

    float2 q = *(const float2*)&Q[(size_t)n * HD + lane * 2];
    const int beg = begp[n], cnt = cntp[n], end = beg + cnt;

    float2 acc = make_float2(0.f, 0.f);
    float zsum = 0.f;

    for (int i = beg; i < end; i += 8) {
        const int m = end - i;                 // wave-uniform, >= 1
        int s[8];
        #pragma unroll
        for (int j = 0; j < 8; ++j) s[j] = (j < m) ? esrc[i + j] : ((void)0, 0);
        if (m < 8) {
            int s0 = s[0];
            #pragma unroll
            for (int j = 1; j < 8; ++j) if (j >= m) s[j] = s0;
        }
        unsigned int ks[8], vs[8];
        #pragma unroll
        for (int j = 0; j < 8; ++j) {
            ks[j] = kv[(size_t)s[j] * 128 + lane];
            vs[j] = kv[(size_t)s[j] * 128 + 64 + lane];
        }
        #pragma unroll
        for (int j = 0; j < 8; ++j) {
            float d = q.x * bflo(ks[j]) + q.y * bfhi(ks[j]);
            d += __shfl_xor(d, 1);
            d += __shfl_xor(d, 2);
            d += __shfl_xor(d, 4);
            float sc = __expf(fminf(fmaxf(d * SQRT_D_INV, -5.f), 5.f));
            float w = (j < m) ? sc : 0.f;
            acc.x += w * bflo(vs[j]);
            acc.y += w * bfhi(vs[j]);
            zsum  += w;
        }
    }

    float inv = 1.f / zsum;
    *(float2*)&out[(size_t)n * HD + lane * 2] = make_float2(acc.x * inv, acc.y * inv);
}

// ---------------- launcher ----------------
extern "C" void kernel_launch(void* const* d_in, const int* in_sizes, int n_in,
                              void* d_out, int out_size, void* d_ws, size_t ws_size,
                              hipStream_t stream) {
    const float* h_src = (const float*)d_in[0];
    const float* h_dst = (const float*)d_in[1];
    const int*   src   = (const int*)d_in[2];
    const int*   dst   = (const int*)d_in[3];
    const float* Qw    = (const float*)d_in[4];
    const float* Qb    = (const float*)d_in[5];
    const float* Kw    = (const float*)d_in[6];
    const float* Kb    = (const float*)d_in[7];
    const float* Vw    = (const float*)d_in[8];
    const float* Vb    = (const float*)d_in[9];
    float* out = (float*)d_out;

    char* ws = (char*)d_ws;
    const size_t q_bytes  = (size_t)N_NODES * HD * sizeof(float);               // 25.6 MB
    const size_t kv_bytes = (size_t)N_NODES * 2 * HD * sizeof(unsigned short);  // 25.6 MB
    const size_t wt_bytes = 3 * 128 * 128 * sizeof(unsigned short);             // 96 KB
    float*          Qp  = (float*)(ws);
    unsigned short* kvp = (unsigned short*)(ws + q_bytes);
    unsigned short* wtp = (unsigned short*)(ws + q_bytes + kv_bytes);
    int* counts = (int*)(ws + q_bytes + kv_bytes + wt_bytes);
    int* total  = counts + N_NODES;           // memset together with counts
    int* beg    = total + 1;
    int* next   = beg + N_NODES;
    int* esrc   = next + N_NODES;

    hipMemsetAsync(counts, 0, (N_NODES + 1) * sizeof(int), stream);

    wtr_kernel<<<192, 256, 0, stream>>>(Qw, Kw, Vw, wtp);

    dim3 pgrid((N_NODES + 63) / 64, 3);
    proj_mfma_kernel<<<pgrid, 256, 0, stream>>>(h_src, h_dst, wtp, Qb, Kb, Vb, Qp, kvp);

    hist_kernel<<<(E_EDGES + 255) / 256, 256, 0, stream>>>(dst, counts);
    offsets_kernel<<<(N_NODES + 255) / 256, 256, 0, stream>>>(counts, beg, next, total);
    scatter_kernel<<<(E_EDGES + 255) / 256, 256, 0, stream>>>(src, dst, next, esrc);

    agg_kernel<<<(N_NODES * 64 + 255) / 256, 256, 0, stream>>>(Qp, (const unsigned int*)kvp,
                                                               beg, counts, esrc, out);
}

// Round 4
// 220.485 us; speedup vs baseline: 1.6471x; 1.0382x over previous
//
#include <hip/hip_runtime.h>
#include <hip/hip_bf16.h>
#include <math.h>

#define N_NODES 50000
#define E_EDGES 800000
#define IN_DIM  128
#define HD      128   // H*D
#define SQRT_D_INV 0.25f

typedef __attribute__((ext_vector_type(8))) short short8v;
typedef __attribute__((ext_vector_type(4))) float float4v;

__device__ inline unsigned short f2bf(float x) {
    __hip_bfloat16 b = __float2bfloat16(x);
    return *reinterpret_cast<unsigned short*>(&b);
}
__device__ inline float bflo(unsigned int u) { return __uint_as_float(u << 16); }
__device__ inline float bfhi(unsigned int u) { return __uint_as_float(u & 0xffff0000u); }

// ---------------- W transpose+convert: wt[which][n][k] = bf16(W[k][n]) ----------------
__global__ __launch_bounds__(256) void wtr_kernel(
    const float* __restrict__ Qw, const float* __restrict__ Kw, const float* __restrict__ Vw,
    unsigned short* __restrict__ wt)
{
    int i = blockIdx.x * 256 + threadIdx.x;          // 3*16384 total
    int which = i >> 14;
    int r = i & 16383;                               // r = k*128 + n
    int k = r >> 7, n = r & 127;
    const float* W = (which == 0) ? Qw : (which == 1) ? Kw : Vw;
    wt[((size_t)which << 14) + n * 128 + k] = f2bf(W[r]);
}

// ---------------- fused MFMA projection: Q,K,V in one pass ----------------
// 256 thr = 4 waves; block owns 64 rows (16/wave). Each wave: load A frags of
// h_dst + h_src once, 3 MFMA phases (acc regs reused), LDS-staged coalesced stores.
__global__ __launch_bounds__(256) void proj_fused_kernel(
    const float* __restrict__ h_src, const float* __restrict__ h_dst,
    const unsigned short* __restrict__ wt,
    const float* __restrict__ Qb, const float* __restrict__ Kb, const float* __restrict__ Vb,
    float* __restrict__ Qo, unsigned short* __restrict__ kv)
{
    __shared__ __align__(16) short sbuf[4][4224];   // 8448 B per wave
    const int t  = threadIdx.x;
    const int wv = t >> 6;
    const int l  = t & 63;
    const int lr = l & 15;       // A-row within tile / B-col within frag
    const int kg = l >> 4;       // k-group 0..3
    const int m_base = blockIdx.x * 64 + wv * 16;
    const int arow = min(m_base + lr, N_NODES - 1);

    const float* pd = h_dst + (size_t)arow * IN_DIM;
    const float* ps = h_src + (size_t)arow * IN_DIM;

    // ---- load all A fragments up front (16 float4 loads in flight) ----
    float4 dr[8], sr[8];
    #pragma unroll
    for (int ks = 0; ks < 4; ++ks) {
        const int k0 = ks * 32 + kg * 8;
        dr[ks * 2]     = *(const float4*)&pd[k0];
        dr[ks * 2 + 1] = *(const float4*)&pd[k0 + 4];
        sr[ks * 2]     = *(const float4*)&ps[k0];
        sr[ks * 2 + 1] = *(const float4*)&ps[k0 + 4];
    }
    short8v afd[4], afs[4];
    #pragma unroll
    for (int ks = 0; ks < 4; ++ks) {
        float4 a0 = dr[ks * 2], a1 = dr[ks * 2 + 1];
        afd[ks][0] = (short)f2bf(a0.x); afd[ks][1] = (short)f2bf(a0.y);
        afd[ks][2] = (short)f2bf(a0.z); afd[ks][3] = (short)f2bf(a0.w);
        afd[ks][4] = (short)f2bf(a1.x); afd[ks][5] = (short)f2bf(a1.y);
        afd[ks][6] = (short)f2bf(a1.z); afd[ks][7] = (short)f2bf(a1.w);
        float4 b0 = sr[ks * 2], b1 = sr[ks * 2 + 1];
        afs[ks][0] = (short)f2bf(b0.x); afs[ks][1] = (short)f2bf(b0.y);
        afs[ks][2] = (short)f2bf(b0.z); afs[ks][3] = (short)f2bf(b0.w);
        afs[ks][4] = (short)f2bf(b1.x); afs[ks][5] = (short)f2bf(b1.y);
        afs[ks][6] = (short)f2bf(b1.z); afs[ks][7] = (short)f2bf(b1.w);
    }

    // ---- phase Q: MFMA + LDS stage (stride 132 floats, 2-way-free banks) ----
    float* qbuf = (float*)&sbuf[wv][0];
    {
        float4v acc[8];
        #pragma unroll
        for (int i = 0; i < 8; ++i) acc[i] = (float4v)0.f;
        #pragma unroll
        for (int ks = 0; ks < 4; ++ks) {
            const int k0 = ks * 32 + kg * 8;
            #pragma unroll
            for (int nf = 0; nf < 8; ++nf) {
                short8v bf = *(const short8v*)&wt[(size_t)(nf * 16 + lr) * 128 + k0];
                acc[nf] = __builtin_amdgcn_mfma_f32_16x16x32_bf16(afd[ks], bf, acc[nf], 0, 0, 0);
            }
        }
        #pragma unroll
        for (int nf = 0; nf < 8; ++nf) {
            const float b = Qb[nf * 16 + lr];
            #pragma unroll
            for (int r = 0; r < 4; ++r)
                qbuf[(kg * 4 + r) * 132 + nf * 16 + lr] = acc[nf][r] + b;
        }
    }
    __syncthreads();
    #pragma unroll
    for (int i = 0; i < 8; ++i) {
        const int elem = i * 256 + l * 4;
        const int row = elem >> 7, col = elem & 127;
        float4 v = *(const float4*)&qbuf[row * 132 + col];
        const int m = m_base + row;
        if (m < N_NODES) *(float4*)&Qo[(size_t)m * HD + col] = v;
    }
    __syncthreads();

    // ---- phases K (which=1) and V (which=2): bf16 stage (stride 136 shorts) ----
    unsigned short* kbuf = (unsigned short*)&sbuf[wv][0];
    #pragma unroll
    for (int which = 1; which <= 2; ++which) {
        float4v acc[8];
        #pragma unroll
        for (int i = 0; i < 8; ++i) acc[i] = (float4v)0.f;
        const unsigned short* W = wt + ((size_t)which << 14);
        #pragma unroll
        for (int ks = 0; ks < 4; ++ks) {
            const int k0 = ks * 32 + kg * 8;
            #pragma unroll
            for (int nf = 0; nf < 8; ++nf) {
                short8v bf = *(const short8v*)&W[(size_t)(nf * 16 + lr) * 128 + k0];
                acc[nf] = __builtin_amdgcn_mfma_f32_16x16x32_bf16(afs[ks], bf, acc[nf], 0, 0, 0);
            }
        }
        const float* bias = (which == 1) ? Kb : Vb;
        #pragma unroll
        for (int nf = 0; nf < 8; ++nf) {
            const float b = bias[nf * 16 + lr];
            #pragma unroll
            for (int r = 0; r < 4; ++r)
                kbuf[(kg * 4 + r) * 136 + nf * 16 + lr] = f2bf(acc[nf][r] + b);
        }
        __syncthreads();
        const int half = (which == 1) ? 0 : HD;
        #pragma unroll
        for (int i = 0; i < 4; ++i) {
            const int s16 = i * 512 + l * 8;
            const int row = s16 >> 7, col = s16 & 127;
            short8v v = *(const short8v*)&kbuf[row * 136 + col];
            const int m = m_base + row;
            if (m < N_NODES) *(short8v*)&kv[(size_t)m * 2 * HD + half + col] = v;
        }
        __syncthreads();
    }
}

// ---------------- CSR build ----------------
__global__ void hist_kernel(const int* __restrict__ dst, int* __restrict__ counts) {
    int e = blockIdx.x * blockDim.x + threadIdx.x;
    if (e < E_EDGES) atomicAdd(&counts[dst[e]], 1);
}

__global__ __launch_bounds__(256) void offsets_kernel(const int* __restrict__ counts,
                                                      int* __restrict__ beg,
                                                      int* __restrict__ next,
                                                      int* __restrict__ total) {
    int i = blockIdx.x * blockDim.x + threadIdx.x;
    int lane = threadIdx.x & 63;
    int v = (i < N_NODES) ? counts[i] : 0;
    int incl = v;
    #pragma unroll
    for (int off = 1; off < 64; off <<= 1) {
        int y = __shfl_up(incl, off);
        if (lane >= off) incl += y;
    }
    int wsum = __shfl(incl, 63);
    int base = 0;
    if (lane == 0) base = atomicAdd(total, wsum);
    base = __shfl(base, 0);
    int b = base + incl - v;
    if (i < N_NODES) { beg[i] = b; next[i] = b; }
}

__global__ void scatter_kernel(const int* __restrict__ src, const int* __restrict__ dst,
                               int* __restrict__ next, int* __restrict__ esrc) {
    int e = blockIdx.x * blockDim.x + threadIdx.x;
    if (e < E_EDGES) {
        int p = atomicAdd(&next[dst[e]], 1);
        esrc[p] = src[e];
    }
}

// ---------------- aggregation: one wave per node, bf16 KV, 8-edge batches ----------------
__global__ __launch_bounds__(256) void agg_kernel(
    const float* __restrict__ Q, const unsigned int* __restrict__ kv,
    const int* __restrict__ begp, const int* __restrict__ cntp,
    const int* __restrict__ esrc, float* __restrict__ out)
{
    int wave = (blockIdx.x * blockDim.x + threadIdx.x) >> 6;
    const int lane = threadIdx.x & 63;
    if (wave >= N_NODES) return;
    const int n = __builtin_amdgcn_readfirstlane(wave);   // wave-uniform -> s_loads

    float2 q = *(const float2*)&Q[(size_t)n * HD + lane * 2];
    const int beg = begp[n], cnt = cntp[n], end = beg + cnt;

    float2 acc = make_float2(0.f, 0.f);
    float zsum = 0.f;

    for (int i = beg; i < end; i += 8) {
        const int m = end - i;                 // wave-uniform, >= 1
        int s[8];
        #pragma unroll
        for (int j = 0; j < 8; ++j) s[j] = (j < m) ? esrc[i + j] : ((void)0, 0);
        if (m < 8) {
            int s0 = s[0];
            #pragma unroll
            for (int j = 1; j < 8; ++j) if (j >= m) s[j] = s0;
        }
        unsigned int ks[8], vs[8];
        #pragma unroll
        for (int j = 0; j < 8; ++j) {
            ks[j] = kv[(size_t)s[j] * 128 + lane];
            vs[j] = kv[(size_t)s[j] * 128 + 64 + lane];
        }
        #pragma unroll
        for (int j = 0; j < 8; ++j) {
            float d = q.x * bflo(ks[j]) + q.y * bfhi(ks[j]);
            d += __shfl_xor(d, 1);
            d += __shfl_xor(d, 2);
            d += __shfl_xor(d, 4);
            float sc = __expf(fminf(fmaxf(d * SQRT_D_INV, -5.f), 5.f));
            float w = (j < m) ? sc : 0.f;
            acc.x += w * bflo(vs[j]);
            acc.y += w * bfhi(vs[j]);
            zsum  += w;
        }
    }

    float inv = 1.f / zsum;
    *(float2*)&out[(size_t)n * HD + lane * 2] = make_float2(acc.x * inv, acc.y * inv);
}

// ---------------- launcher ----------------
extern "C" void kernel_launch(void* const* d_in, const int* in_sizes, int n_in,
                              void* d_out, int out_size, void* d_ws, size_t ws_size,
                              hipStream_t stream) {
    const float* h_src = (const float*)d_in[0];
    const float* h_dst = (const float*)d_in[1];
    const int*   src   = (const int*)d_in[2];
    const int*   dst   = (const int*)d_in[3];
    const float* Qw    = (const float*)d_in[4];
    const float* Qb    = (const float*)d_in[5];
    const float* Kw    = (const float*)d_in[6];
    const float* Kb    = (const float*)d_in[7];
    const float* Vw    = (const float*)d_in[8];
    const float* Vb    = (const float*)d_in[9];
    float* out = (float*)d_out;

    char* ws = (char*)d_ws;
    const size_t q_bytes  = (size_t)N_NODES * HD * sizeof(float);               // 25.6 MB
    const size_t kv_bytes = (size_t)N_NODES * 2 * HD * sizeof(unsigned short);  // 25.6 MB
    const size_t wt_bytes = 3 * 128 * 128 * sizeof(unsigned short);             // 96 KB
    float*          Qp  = (float*)(ws);
    unsigned short* kvp = (unsigned short*)(ws + q_bytes);
    unsigned short* wtp = (unsigned short*)(ws + q_bytes + kv_bytes);
    int* counts = (int*)(ws + q_bytes + kv_bytes + wt_bytes);
    int* total  = counts + N_NODES;           // memset together with counts
    int* beg    = total + 1;
    int* next   = beg + N_NODES;
    int* esrc   = next + N_NODES;

    hipMemsetAsync(counts, 0, (N_NODES + 1) * sizeof(int), stream);

    wtr_kernel<<<192, 256, 0, stream>>>(Qw, Kw, Vw, wtp);

    proj_fused_kernel<<<(N_NODES + 63) / 64, 256, 0, stream>>>(
        h_src, h_dst, wtp, Qb, Kb, Vb, Qp, kvp);

    hist_kernel<<<(E_EDGES + 255) / 256, 256, 0, stream>>>(dst, counts);
    offsets_kernel<<<(N_NODES + 255) / 256, 256, 0, stream>>>(counts, beg, next, total);
    scatter_kernel<<<(E_EDGES + 255) / 256, 256, 0, stream>>>(src, dst, next, esrc);

    agg_kernel<<<(N_NODES * 64 + 255) / 256, 256, 0, stream>>>(Qp, (const unsigned int*)kvp,
                                                               beg, counts, esrc, out);
}

// Round 5
// 165.065 us; speedup vs baseline: 2.2001x; 1.3357x over previous
//
#include <hip/hip_runtime.h>
#include <hip/hip_bf16.h>
#include <math.h>

#define N_NODES 50000
#define E_EDGES 800000
#define IN_DIM  128
#define HD      128   // H*D
#define SQRT_D_INV 0.25f

#define PROJ_BLOCKS ((N_NODES + 63) / 64)   // 782
#define HIST_BLOCKS 1024

typedef __attribute__((ext_vector_type(8))) short short8v;
typedef __attribute__((ext_vector_type(4))) float float4v;

__device__ inline unsigned short f2bf(float x) {
    __hip_bfloat16 b = __float2bfloat16(x);
    return *reinterpret_cast<unsigned short*>(&b);
}
__device__ inline float bflo(unsigned int u) { return __uint_as_float(u << 16); }
__device__ inline float bfhi(unsigned int u) { return __uint_as_float(u & 0xffff0000u); }

// ---------------- W transpose+convert: wt[which][n][k] = bf16(W[k][n]) ----------------
__global__ __launch_bounds__(256) void wtr_kernel(
    const float* __restrict__ Qw, const float* __restrict__ Kw, const float* __restrict__ Vw,
    unsigned short* __restrict__ wt)
{
    int i = blockIdx.x * 256 + threadIdx.x;          // 3*16384 total
    int which = i >> 14;
    int r = i & 16383;                               // r = k*128 + n
    int k = r >> 7, n = r & 127;
    const float* W = (which == 0) ? Qw : (which == 1) ? Kw : Vw;
    wt[((size_t)which << 14) + n * 128 + k] = f2bf(W[r]);
}

// ---------------- fused proj (Q|K|V -> qkv bf16 rows) + edge histogram+rank ----------
// blocks [0, PROJ_BLOCKS): projection, 64 rows/block (16/wave), 4 waves.
// blocks [PROJ_BLOCKS, +HIST_BLOCKS): rank[e] = atomicAdd(&counts[dst[e]], 1).
__global__ __launch_bounds__(256) void proj_hist_kernel(
    const float* __restrict__ h_src, const float* __restrict__ h_dst,
    const unsigned short* __restrict__ wt,
    const float* __restrict__ Qb, const float* __restrict__ Kb, const float* __restrict__ Vb,
    unsigned short* __restrict__ qkv,
    const int* __restrict__ dst, int* __restrict__ counts, int* __restrict__ rank)
{
    if (blockIdx.x >= PROJ_BLOCKS) {
        int tid = (blockIdx.x - PROJ_BLOCKS) * 256 + threadIdx.x;
        for (int e = tid; e < E_EDGES; e += HIST_BLOCKS * 256)
            rank[e] = atomicAdd(&counts[dst[e]], 1);
        return;
    }

    __shared__ __align__(16) short sbuf[4][4224];   // 8448 B per wave
    const int t  = threadIdx.x;
    const int wv = t >> 6;
    const int l  = t & 63;
    const int lr = l & 15;       // A-row within tile / B-col within frag
    const int kg = l >> 4;       // k-group 0..3
    const int m_base = blockIdx.x * 64 + wv * 16;
    const int arow = min(m_base + lr, N_NODES - 1);

    const float* pd = h_dst + (size_t)arow * IN_DIM;
    const float* ps = h_src + (size_t)arow * IN_DIM;

    // A fragments for h_dst (Q) and h_src (K,V): 16 float4 loads in flight
    short8v afd[4], afs[4];
    #pragma unroll
    for (int ks = 0; ks < 4; ++ks) {
        const int k0 = ks * 32 + kg * 8;
        float4 a0 = *(const float4*)&pd[k0];
        float4 a1 = *(const float4*)&pd[k0 + 4];
        float4 b0 = *(const float4*)&ps[k0];
        float4 b1 = *(const float4*)&ps[k0 + 4];
        afd[ks][0] = (short)f2bf(a0.x); afd[ks][1] = (short)f2bf(a0.y);
        afd[ks][2] = (short)f2bf(a0.z); afd[ks][3] = (short)f2bf(a0.w);
        afd[ks][4] = (short)f2bf(a1.x); afd[ks][5] = (short)f2bf(a1.y);
        afd[ks][6] = (short)f2bf(a1.z); afd[ks][7] = (short)f2bf(a1.w);
        afs[ks][0] = (short)f2bf(b0.x); afs[ks][1] = (short)f2bf(b0.y);
        afs[ks][2] = (short)f2bf(b0.z); afs[ks][3] = (short)f2bf(b0.w);
        afs[ks][4] = (short)f2bf(b1.x); afs[ks][5] = (short)f2bf(b1.y);
        afs[ks][6] = (short)f2bf(b1.z); afs[ks][7] = (short)f2bf(b1.w);
    }

    unsigned short* buf = (unsigned short*)&sbuf[wv][0];

    // ---- phase Q ----
    {
        float4v acc[8];
        #pragma unroll
        for (int i = 0; i < 8; ++i) acc[i] = (float4v)0.f;
        #pragma unroll
        for (int ks = 0; ks < 4; ++ks) {
            const int k0 = ks * 32 + kg * 8;
            #pragma unroll
            for (int nf = 0; nf < 8; ++nf) {
                short8v bf = *(const short8v*)&wt[(size_t)(nf * 16 + lr) * 128 + k0];
                acc[nf] = __builtin_amdgcn_mfma_f32_16x16x32_bf16(afd[ks], bf, acc[nf], 0, 0, 0);
            }
        }
        #pragma unroll
        for (int nf = 0; nf < 8; ++nf) {
            const float b = Qb[nf * 16 + lr];
            #pragma unroll
            for (int r = 0; r < 4; ++r)
                buf[(kg * 4 + r) * 136 + nf * 16 + lr] = f2bf(acc[nf][r] + b);
        }
    }
    __syncthreads();
    #pragma unroll
    for (int i = 0; i < 4; ++i) {
        const int chunk = i * 64 + l;        // 256 chunks of 8 shorts = 16 rows x 128
        const int row = chunk >> 4;
        const int c   = (chunk & 15) * 8;
        const int m = m_base + row;
        short8v v = *(const short8v*)&buf[row * 136 + c];
        if (m < N_NODES) *(short8v*)&qkv[(size_t)m * 384 + c] = v;
    }
    __syncthreads();

    // ---- phase K+V merged (64 B-loads in flight) ----
    {
        float4v accK[8], accV[8];
        #pragma unroll
        for (int i = 0; i < 8; ++i) { accK[i] = (float4v)0.f; accV[i] = (float4v)0.f; }
        const unsigned short* WK = wt + (1 << 14);
        const unsigned short* WV = wt + (2 << 14);
        #pragma unroll
        for (int ks = 0; ks < 4; ++ks) {
            const int k0 = ks * 32 + kg * 8;
            #pragma unroll
            for (int nf = 0; nf < 8; ++nf) {
                short8v bk = *(const short8v*)&WK[(size_t)(nf * 16 + lr) * 128 + k0];
                short8v bv = *(const short8v*)&WV[(size_t)(nf * 16 + lr) * 128 + k0];
                accK[nf] = __builtin_amdgcn_mfma_f32_16x16x32_bf16(afs[ks], bk, accK[nf], 0, 0, 0);
                accV[nf] = __builtin_amdgcn_mfma_f32_16x16x32_bf16(afs[ks], bv, accV[nf], 0, 0, 0);
            }
        }
        #pragma unroll
        for (int nf = 0; nf < 8; ++nf) {
            const float bk = Kb[nf * 16 + lr], bv = Vb[nf * 16 + lr];
            #pragma unroll
            for (int r = 0; r < 4; ++r) {
                buf[(kg * 4 + r) * 264 + nf * 16 + lr]       = f2bf(accK[nf][r] + bk);
                buf[(kg * 4 + r) * 264 + 128 + nf * 16 + lr] = f2bf(accV[nf][r] + bv);
            }
        }
    }
    __syncthreads();
    #pragma unroll
    for (int i = 0; i < 8; ++i) {
        const int chunk = i * 64 + l;        // 512 chunks of 8 shorts = 16 rows x 256
        const int row = chunk >> 5;
        const int c   = (chunk & 31) * 8;
        const int m = m_base + row;
        short8v v = *(const short8v*)&buf[row * 264 + c];
        if (m < N_NODES) *(short8v*)&qkv[(size_t)m * 384 + 128 + c] = v;
    }
}

// ---------------- offsets: wave scan + one atomic per wave -> beg[] ----------------
__global__ __launch_bounds__(256) void offsets_kernel(const int* __restrict__ counts,
                                                      int* __restrict__ beg,
                                                      int* __restrict__ total) {
    int i = blockIdx.x * blockDim.x + threadIdx.x;
    int lane = threadIdx.x & 63;
    int v = (i < N_NODES) ? counts[i] : 0;
    int incl = v;
    #pragma unroll
    for (int off = 1; off < 64; off <<= 1) {
        int y = __shfl_up(incl, off);
        if (lane >= off) incl += y;
    }
    int wsum = __shfl(incl, 63);
    int base = 0;
    if (lane == 0) base = atomicAdd(total, wsum);
    base = __shfl(base, 0);
    if (i < N_NODES) beg[i] = base + incl - v;
}

// ---------------- scatter: atomic-free via precomputed rank ----------------
__global__ void scatter_kernel(const int* __restrict__ src, const int* __restrict__ dst,
                               const int* __restrict__ beg, const int* __restrict__ rank,
                               int* __restrict__ esrc) {
    int e = blockIdx.x * blockDim.x + threadIdx.x;
    if (e < E_EDGES) esrc[beg[dst[e]] + rank[e]] = src[e];
}

// ---------------- aggregation: one wave per node; lane = (e-slot, 8-channel chunk) ----
// lane l: e = l>>4 (4 edge slots), u = l&15 (channels u*8..u*8+7, head u>>1).
// dot = 8 in-lane FMA + 1 shfl_xor(1); PV accum in-lane; butterfly (16,32) per node.
__global__ __launch_bounds__(256) void agg_kernel(
    const unsigned short* __restrict__ qkv,
    const int* __restrict__ begp, const int* __restrict__ cntp,
    const int* __restrict__ esrc, float* __restrict__ out)
{
    int wave = (blockIdx.x * blockDim.x + threadIdx.x) >> 6;
    const int lane = threadIdx.x & 63;
    if (wave >= N_NODES) return;
    const int n = __builtin_amdgcn_readfirstlane(wave);
    const int e = lane >> 4;
    const int u = lane & 15;

    const uint4 qv = *(const uint4*)&qkv[(size_t)n * 384 + u * 8];
    const float q0 = bflo(qv.x), q1 = bfhi(qv.x), q2 = bflo(qv.y), q3 = bfhi(qv.y);
    const float q4 = bflo(qv.z), q5 = bfhi(qv.z), q6 = bflo(qv.w), q7 = bfhi(qv.w);

    const int b0 = begp[n], c0 = cntp[n], endp = b0 + c0;

    float a0=0.f,a1=0.f,a2=0.f,a3=0.f,a4=0.f,a5=0.f,a6=0.f,a7=0.f, z=0.f;

    for (int base = b0; base < endp; base += 4) {
        const int i  = base + e;
        const int iv = min(i, endp - 1);
        const int s  = esrc[iv];
        const size_t ro = (size_t)s * 384;
        const uint4 kk = *(const uint4*)&qkv[ro + 128 + u * 8];
        const uint4 vv = *(const uint4*)&qkv[ro + 256 + u * 8];
        float d =      q0 * bflo(kk.x);
        d = fmaf(q1, bfhi(kk.x), d);
        d = fmaf(q2, bflo(kk.y), d);
        d = fmaf(q3, bfhi(kk.y), d);
        d = fmaf(q4, bflo(kk.z), d);
        d = fmaf(q5, bfhi(kk.z), d);
        d = fmaf(q6, bflo(kk.w), d);
        d = fmaf(q7, bfhi(kk.w), d);
        d += __shfl_xor(d, 1);                       // combine the two half-head lanes
        float sc = __expf(fminf(fmaxf(d * SQRT_D_INV, -5.f), 5.f));
        float w = (i < endp) ? sc : 0.f;
        z += w;
        a0 = fmaf(w, bflo(vv.x), a0);
        a1 = fmaf(w, bfhi(vv.x), a1);
        a2 = fmaf(w, bflo(vv.y), a2);
        a3 = fmaf(w, bfhi(vv.y), a3);
        a4 = fmaf(w, bflo(vv.z), a4);
        a5 = fmaf(w, bfhi(vv.z), a5);
        a6 = fmaf(w, bflo(vv.w), a6);
        a7 = fmaf(w, bfhi(vv.w), a7);
    }

    #pragma unroll
    for (int mask = 16; mask <= 32; mask <<= 1) {
        z  += __shfl_xor(z, mask);
        a0 += __shfl_xor(a0, mask);
        a1 += __shfl_xor(a1, mask);
        a2 += __shfl_xor(a2, mask);
        a3 += __shfl_xor(a3, mask);
        a4 += __shfl_xor(a4, mask);
        a5 += __shfl_xor(a5, mask);
        a6 += __shfl_xor(a6, mask);
        a7 += __shfl_xor(a7, mask);
    }

    const float inv = 1.f / z;     // deg==0 -> 0*inf = NaN, matching reference 0/0
    if (e == 0) {
        *(float4*)&out[(size_t)n * HD + u * 8]     = make_float4(a0*inv, a1*inv, a2*inv, a3*inv);
        *(float4*)&out[(size_t)n * HD + u * 8 + 4] = make_float4(a4*inv, a5*inv, a6*inv, a7*inv);
    }
}

// ---------------- launcher ----------------
extern "C" void kernel_launch(void* const* d_in, const int* in_sizes, int n_in,
                              void* d_out, int out_size, void* d_ws, size_t ws_size,
                              hipStream_t stream) {
    const float* h_src = (const float*)d_in[0];
    const float* h_dst = (const float*)d_in[1];
    const int*   src   = (const int*)d_in[2];
    const int*   dst   = (const int*)d_in[3];
    const float* Qw    = (const float*)d_in[4];
    const float* Qb    = (const float*)d_in[5];
    const float* Kw    = (const float*)d_in[6];
    const float* Kb    = (const float*)d_in[7];
    const float* Vw    = (const float*)d_in[8];
    const float* Vb    = (const float*)d_in[9];
    float* out = (float*)d_out;

    char* ws = (char*)d_ws;
    const size_t qkv_bytes = (size_t)N_NODES * 384 * sizeof(unsigned short);  // 38.4 MB
    const size_t wt_bytes  = 3 * 128 * 128 * sizeof(unsigned short);          // 96 KB
    unsigned short* qkvp = (unsigned short*)(ws);
    unsigned short* wtp  = (unsigned short*)(ws + qkv_bytes);
    int* counts = (int*)(ws + qkv_bytes + wt_bytes);
    int* total  = counts + N_NODES;     // zeroed with counts
    int* beg    = total + 1;
    int* rank   = beg + N_NODES;
    int* esrc   = rank + E_EDGES;

    hipMemsetAsync(counts, 0, (N_NODES + 1) * sizeof(int), stream);

    wtr_kernel<<<192, 256, 0, stream>>>(Qw, Kw, Vw, wtp);

    proj_hist_kernel<<<PROJ_BLOCKS + HIST_BLOCKS, 256, 0, stream>>>(
        h_src, h_dst, wtp, Qb, Kb, Vb, qkvp, dst, counts, rank);

    offsets_kernel<<<(N_NODES + 255) / 256, 256, 0, stream>>>(counts, beg, total);

    scatter_kernel<<<(E_EDGES + 255) / 256, 256, 0, stream>>>(src, dst, beg, rank, esrc);

    agg_kernel<<<(N_NODES * 64 + 255) / 256, 256, 0, stream>>>(qkvp, beg, counts, esrc, out);
}

// Round 6
// 142.928 us; speedup vs baseline: 2.5408x; 1.1549x over previous
//
#include <hip/hip_runtime.h>
#include <hip/hip_bf16.h>
#include <math.h>

#define N_NODES 50000
#define E_EDGES 800000
#define IN_DIM  128
#define HD      128   // H*D
#define SQRT_D_INV 0.25f

#define PROJ_BLOCKS ((N_NODES + 63) / 64)   // 782
#define HIST_BLOCKS 1024

typedef __attribute__((ext_vector_type(8))) short short8v;
typedef __attribute__((ext_vector_type(4))) float float4v;

__device__ inline unsigned short f2bf(float x) {
    __hip_bfloat16 b = __float2bfloat16(x);
    return *reinterpret_cast<unsigned short*>(&b);
}
__device__ inline float bflo(unsigned int u) { return __uint_as_float(u << 16); }
__device__ inline float bfhi(unsigned int u) { return __uint_as_float(u & 0xffff0000u); }

// ---------------- W transpose+convert + zero counts ----------------
// wt[which][n][k] = bf16(W[k][n]);  counts[0..N_NODES] = 0 (incl. total slot)
__global__ __launch_bounds__(256) void wtr_init_kernel(
    const float* __restrict__ Qw, const float* __restrict__ Kw, const float* __restrict__ Vw,
    unsigned short* __restrict__ wt, int* __restrict__ counts)
{
    int i = blockIdx.x * 256 + threadIdx.x;          // 196*256 = 50176 threads
    if (i <= N_NODES) counts[i] = 0;
    if (i < 3 * 16384) {
        int which = i >> 14;
        int r = i & 16383;                           // r = k*128 + n
        int k = r >> 7, n = r & 127;
        const float* W = (which == 0) ? Qw : (which == 1) ? Kw : Vw;
        wt[((size_t)which << 14) + n * 128 + k] = f2bf(W[r]);
    }
}

// ---------------- fused hist (blocks [0,HIST)) + proj (blocks [HIST,+PROJ)) ----------
// proj: 64 rows/block (16/wave). Per phase (Q,K,V): stage 32KB W in LDS (coalesced,
// XOR-swizzled), MFMA with ds_read_b128 B-fragments, re-stage outputs over the W
// region, coalesced 16B global stores.
__global__ __launch_bounds__(256) void proj_hist_kernel(
    const float* __restrict__ h_src, const float* __restrict__ h_dst,
    const unsigned short* __restrict__ wt,
    const float* __restrict__ Qb, const float* __restrict__ Kb, const float* __restrict__ Vb,
    unsigned short* __restrict__ qkv,
    const int* __restrict__ dst, int* __restrict__ counts, int* __restrict__ rank)
{
    if (blockIdx.x < HIST_BLOCKS) {
        int tid = blockIdx.x * 256 + threadIdx.x;
        for (int e = tid; e < E_EDGES; e += HIST_BLOCKS * 256)
            rank[e] = atomicAdd(&counts[dst[e]], 1);
        return;
    }

    __shared__ __align__(16) unsigned short smem[16384];   // 32 KB: W stage / output stage overlay
    const int t  = threadIdx.x;
    const int wv = t >> 6;
    const int l  = t & 63;
    const int lr = l & 15;       // A-row within tile / B-col within frag
    const int kg = l >> 4;       // k-group 0..3
    const int m_base = (blockIdx.x - HIST_BLOCKS) * 64 + wv * 16;
    const int arow = min(m_base + lr, N_NODES - 1);

    const float* pd = h_dst + (size_t)arow * IN_DIM;
    const float* ps = h_src + (size_t)arow * IN_DIM;

    // A fragments for h_dst (Q) and h_src (K,V): 16 float4 loads in flight
    short8v afd[4], afs[4];
    #pragma unroll
    for (int ks = 0; ks < 4; ++ks) {
        const int k0 = ks * 32 + kg * 8;
        float4 a0 = *(const float4*)&pd[k0];
        float4 a1 = *(const float4*)&pd[k0 + 4];
        float4 b0 = *(const float4*)&ps[k0];
        float4 b1 = *(const float4*)&ps[k0 + 4];
        afd[ks][0] = (short)f2bf(a0.x); afd[ks][1] = (short)f2bf(a0.y);
        afd[ks][2] = (short)f2bf(a0.z); afd[ks][3] = (short)f2bf(a0.w);
        afd[ks][4] = (short)f2bf(a1.x); afd[ks][5] = (short)f2bf(a1.y);
        afd[ks][6] = (short)f2bf(a1.z); afd[ks][7] = (short)f2bf(a1.w);
        afs[ks][0] = (short)f2bf(b0.x); afs[ks][1] = (short)f2bf(b0.y);
        afs[ks][2] = (short)f2bf(b0.z); afs[ks][3] = (short)f2bf(b0.w);
        afs[ks][4] = (short)f2bf(b1.x); afs[ks][5] = (short)f2bf(b1.y);
        afs[ks][6] = (short)f2bf(b1.z); afs[ks][7] = (short)f2bf(b1.w);
    }

    unsigned short* stg = &smem[wv * 4224];    // 2176 shorts used per wave (overlays W)

    #pragma unroll
    for (int phase = 0; phase < 3; ++phase) {
        if (phase) __syncthreads();            // everyone done with prev stage region
        // ---- cooperative W[phase] -> LDS, swizzled: byte d -> d ^ (((d>>8)&7)<<4) ----
        const unsigned short* wsrc = wt + ((size_t)phase << 14);
        #pragma unroll
        for (int j = 0; j < 8; ++j) {
            const int selem = j * 2048 + t * 8;              // short index, 16B chunks
            const int d = selem * 2;                         // linear byte addr
            const int sd = d ^ (((d >> 8) & 7) << 4);        // swizzled byte addr
            *(short8v*)((char*)smem + sd) = *(const short8v*)&wsrc[selem];
        }
        __syncthreads();

        // ---- MFMA: B-fragments from LDS ----
        const short8v* aF = (phase == 0) ? afd : afs;
        float4v acc[8];
        #pragma unroll
        for (int i = 0; i < 8; ++i) acc[i] = (float4v)0.f;
        #pragma unroll
        for (int ks = 0; ks < 4; ++ks) {
            #pragma unroll
            for (int nf = 0; nf < 8; ++nf) {
                const int a = (nf * 16 + lr) * 256 + ks * 64 + kg * 16;
                const int sa = a ^ ((lr & 7) << 4);
                short8v bf = *(const short8v*)((const char*)smem + sa);
                acc[nf] = __builtin_amdgcn_mfma_f32_16x16x32_bf16(aF[ks], bf, acc[nf], 0, 0, 0);
            }
        }
        __syncthreads();                       // all waves done reading W

        // ---- stage outputs (own region), then coalesced stores ----
        const float* bias = (phase == 0) ? Qb : (phase == 1) ? Kb : Vb;
        #pragma unroll
        for (int nf = 0; nf < 8; ++nf) {
            const float b = bias[nf * 16 + lr];
            #pragma unroll
            for (int r = 0; r < 4; ++r)
                stg[(kg * 4 + r) * 136 + nf * 16 + lr] = f2bf(acc[nf][r] + b);
        }
        #pragma unroll
        for (int i = 0; i < 4; ++i) {
            const int chunk = i * 64 + l;      // 256 chunks of 8 shorts = 16 rows x 128
            const int row = chunk >> 4;
            const int c   = (chunk & 15) * 8;
            const int m = m_base + row;
            short8v v = *(const short8v*)&stg[row * 136 + c];
            if (m < N_NODES) *(short8v*)&qkv[(size_t)m * 384 + phase * 128 + c] = v;
        }
    }
}

// ---------------- offsets: wave scan + one atomic per wave -> beg[] ----------------
__global__ __launch_bounds__(256) void offsets_kernel(const int* __restrict__ counts,
                                                      int* __restrict__ beg,
                                                      int* __restrict__ total) {
    int i = blockIdx.x * blockDim.x + threadIdx.x;
    int lane = threadIdx.x & 63;
    int v = (i < N_NODES) ? counts[i] : 0;
    int incl = v;
    #pragma unroll
    for (int off = 1; off < 64; off <<= 1) {
        int y = __shfl_up(incl, off);
        if (lane >= off) incl += y;
    }
    int wsum = __shfl(incl, 63);
    int base = 0;
    if (lane == 0) base = atomicAdd(total, wsum);
    base = __shfl(base, 0);
    if (i < N_NODES) beg[i] = base + incl - v;
}

// ---------------- scatter: atomic-free via precomputed rank ----------------
__global__ void scatter_kernel(const int* __restrict__ src, const int* __restrict__ dst,
                               const int* __restrict__ beg, const int* __restrict__ rank,
                               int* __restrict__ esrc) {
    int e = blockIdx.x * blockDim.x + threadIdx.x;
    if (e < E_EDGES) esrc[beg[dst[e]] + rank[e]] = src[e];
}

// ---------------- aggregation: one wave per node; lane = (e-slot 0..3, chunk u 0..15) ----
// 2x unrolled: 8 edges / iteration, 16 row-loads + 2 idx-loads in flight.
__global__ __launch_bounds__(256) void agg_kernel(
    const unsigned short* __restrict__ qkv,
    const int* __restrict__ begp, const int* __restrict__ cntp,
    const int* __restrict__ esrc, float* __restrict__ out)
{
    int wave = (blockIdx.x * blockDim.x + threadIdx.x) >> 6;
    const int lane = threadIdx.x & 63;
    if (wave >= N_NODES) return;
    const int n = __builtin_amdgcn_readfirstlane(wave);
    const int e = lane >> 4;
    const int u = lane & 15;

    const uint4 qv = *(const uint4*)&qkv[(size_t)n * 384 + u * 8];
    const float q0 = bflo(qv.x), q1 = bfhi(qv.x), q2 = bflo(qv.y), q3 = bfhi(qv.y);
    const float q4 = bflo(qv.z), q5 = bfhi(qv.z), q6 = bflo(qv.w), q7 = bfhi(qv.w);

    const int b0 = begp[n], c0 = cntp[n], endp = b0 + c0;

    float a0=0.f,a1=0.f,a2=0.f,a3=0.f,a4=0.f,a5=0.f,a6=0.f,a7=0.f, z=0.f;

    for (int base = b0; base < endp; base += 8) {
        const int i0 = base + e;
        const int i1 = base + 4 + e;
        const int s0 = esrc[min(i0, endp - 1)];
        const int s1 = esrc[min(i1, endp - 1)];
        const size_t r0 = (size_t)s0 * 384, r1 = (size_t)s1 * 384;
        const uint4 kk0 = *(const uint4*)&qkv[r0 + 128 + u * 8];
        const uint4 vv0 = *(const uint4*)&qkv[r0 + 256 + u * 8];
        const uint4 kk1 = *(const uint4*)&qkv[r1 + 128 + u * 8];
        const uint4 vv1 = *(const uint4*)&qkv[r1 + 256 + u * 8];

        float d0 =      q0 * bflo(kk0.x);
        d0 = fmaf(q1, bfhi(kk0.x), d0);
        d0 = fmaf(q2, bflo(kk0.y), d0);
        d0 = fmaf(q3, bfhi(kk0.y), d0);
        d0 = fmaf(q4, bflo(kk0.z), d0);
        d0 = fmaf(q5, bfhi(kk0.z), d0);
        d0 = fmaf(q6, bflo(kk0.w), d0);
        d0 = fmaf(q7, bfhi(kk0.w), d0);
        d0 += __shfl_xor(d0, 1);
        float w0 = (i0 < endp) ? __expf(fminf(fmaxf(d0 * SQRT_D_INV, -5.f), 5.f)) : 0.f;
        z += w0;
        a0 = fmaf(w0, bflo(vv0.x), a0);
        a1 = fmaf(w0, bfhi(vv0.x), a1);
        a2 = fmaf(w0, bflo(vv0.y), a2);
        a3 = fmaf(w0, bfhi(vv0.y), a3);
        a4 = fmaf(w0, bflo(vv0.z), a4);
        a5 = fmaf(w0, bfhi(vv0.z), a5);
        a6 = fmaf(w0, bflo(vv0.w), a6);
        a7 = fmaf(w0, bfhi(vv0.w), a7);

        float d1 =      q0 * bflo(kk1.x);
        d1 = fmaf(q1, bfhi(kk1.x), d1);
        d1 = fmaf(q2, bflo(kk1.y), d1);
        d1 = fmaf(q3, bfhi(kk1.y), d1);
        d1 = fmaf(q4, bflo(kk1.z), d1);
        d1 = fmaf(q5, bfhi(kk1.z), d1);
        d1 = fmaf(q6, bflo(kk1.w), d1);
        d1 = fmaf(q7, bfhi(kk1.w), d1);
        d1 += __shfl_xor(d1, 1);
        float w1 = (i1 < endp) ? __expf(fminf(fmaxf(d1 * SQRT_D_INV, -5.f), 5.f)) : 0.f;
        z += w1;
        a0 = fmaf(w1, bflo(vv1.x), a0);
        a1 = fmaf(w1, bfhi(vv1.x), a1);
        a2 = fmaf(w1, bflo(vv1.y), a2);
        a3 = fmaf(w1, bfhi(vv1.y), a3);
        a4 = fmaf(w1, bflo(vv1.z), a4);
        a5 = fmaf(w1, bfhi(vv1.z), a5);
        a6 = fmaf(w1, bflo(vv1.w), a6);
        a7 = fmaf(w1, bfhi(vv1.w), a7);
    }

    #pragma unroll
    for (int mask = 16; mask <= 32; mask <<= 1) {
        z  += __shfl_xor(z, mask);
        a0 += __shfl_xor(a0, mask);
        a1 += __shfl_xor(a1, mask);
        a2 += __shfl_xor(a2, mask);
        a3 += __shfl_xor(a3, mask);
        a4 += __shfl_xor(a4, mask);
        a5 += __shfl_xor(a5, mask);
        a6 += __shfl_xor(a6, mask);
        a7 += __shfl_xor(a7, mask);
    }

    const float inv = 1.f / z;     // deg==0 -> 0*inf = NaN, matching reference 0/0
    if (e == 0) {
        *(float4*)&out[(size_t)n * HD + u * 8]     = make_float4(a0*inv, a1*inv, a2*inv, a3*inv);
        *(float4*)&out[(size_t)n * HD + u * 8 + 4] = make_float4(a4*inv, a5*inv, a6*inv, a7*inv);
    }
}

// ---------------- launcher ----------------
extern "C" void kernel_launch(void* const* d_in, const int* in_sizes, int n_in,
                              void* d_out, int out_size, void* d_ws, size_t ws_size,
                              hipStream_t stream) {
    const float* h_src = (const float*)d_in[0];
    const float* h_dst = (const float*)d_in[1];
    const int*   src   = (const int*)d_in[2];
    const int*   dst   = (const int*)d_in[3];
    const float* Qw    = (const float*)d_in[4];
    const float* Qb    = (const float*)d_in[5];
    const float* Kw    = (const float*)d_in[6];
    const float* Kb    = (const float*)d_in[7];
    const float* Vw    = (const float*)d_in[8];
    const float* Vb    = (const float*)d_in[9];
    float* out = (float*)d_out;

    char* ws = (char*)d_ws;
    const size_t qkv_bytes = (size_t)N_NODES * 384 * sizeof(unsigned short);  // 38.4 MB
    const size_t wt_bytes  = 3 * 128 * 128 * sizeof(unsigned short);          // 96 KB
    unsigned short* qkvp = (unsigned short*)(ws);
    unsigned short* wtp  = (unsigned short*)(ws + qkv_bytes);
    int* counts = (int*)(ws + qkv_bytes + wt_bytes);
    int* total  = counts + N_NODES;     // zeroed by wtr_init
    int* beg    = total + 1;
    int* rank   = beg + N_NODES;
    int* esrc   = rank + E_EDGES;

    wtr_init_kernel<<<196, 256, 0, stream>>>(Qw, Kw, Vw, wtp, counts);

    proj_hist_kernel<<<HIST_BLOCKS + PROJ_BLOCKS, 256, 0, stream>>>(
        h_src, h_dst, wtp, Qb, Kb, Vb, qkvp, dst, counts, rank);

    offsets_kernel<<<(N_NODES + 255) / 256, 256, 0, stream>>>(counts, beg, total);

    scatter_kernel<<<(E_EDGES + 255) / 256, 256, 0, stream>>>(src, dst, beg, rank, esrc);

    agg_kernel<<<(N_NODES * 64 + 255) / 256, 256, 0, stream>>>(qkvp, beg, counts, esrc, out);
}

// Round 7
// 139.011 us; speedup vs baseline: 2.6124x; 1.0282x over previous
//
#include <hip/hip_runtime.h>
#include <hip/hip_bf16.h>
#include <math.h>

#define N_NODES 50000
#define E_EDGES 800000
#define IN_DIM  128
#define HD      128   // H*D
#define SQRT_D_INV 0.25f

#define PROJ_BLOCKS ((N_NODES + 63) / 64)   // 782
#define HIST_BLOCKS 1024                    // must stay 1024: scatter derives c=(e>>8)&7

typedef __attribute__((ext_vector_type(8))) short short8v;
typedef __attribute__((ext_vector_type(4))) float float4v;

__device__ inline unsigned short f2bf(float x) {
    __hip_bfloat16 b = __float2bfloat16(x);
    return *reinterpret_cast<unsigned short*>(&b);
}
__device__ inline float bflo(unsigned int u) { return __uint_as_float(u << 16); }
__device__ inline float bfhi(unsigned int u) { return __uint_as_float(u & 0xffff0000u); }

// ---------------- W transpose+convert + zero counts8 ----------------
// wt[which][n][k] = bf16(W[k][n]);  counts8[0 .. 8*N_NODES] = 0 (incl. total slot)
__global__ __launch_bounds__(256) void wtr_init_kernel(
    const float* __restrict__ Qw, const float* __restrict__ Kw, const float* __restrict__ Vw,
    unsigned short* __restrict__ wt, int* __restrict__ counts8)
{
    int i = blockIdx.x * 256 + threadIdx.x;          // 392*256 = 100352 threads
    for (int j = i; j <= 8 * N_NODES; j += 392 * 256) counts8[j] = 0;
    if (i < 3 * 16384) {
        int which = i >> 14;
        int r = i & 16383;                           // r = k*128 + n
        int k = r >> 7, n = r & 127;
        const float* W = (which == 0) ? Qw : (which == 1) ? Kw : Vw;
        wt[((size_t)which << 14) + n * 128 + k] = f2bf(W[r]);
    }
}

// ---------------- fused hist (blocks [0,HIST)) + proj (blocks [HIST,+PROJ)) ----------
// hist: 8-way privatized counters, copy c = blockIdx&7 (XCD-local on round-robin
// dispatch heuristic; correctness independent of actual placement).
__global__ __launch_bounds__(256) void proj_hist_kernel(
    const float* __restrict__ h_src, const float* __restrict__ h_dst,
    const unsigned short* __restrict__ wt,
    const float* __restrict__ Qb, const float* __restrict__ Kb, const float* __restrict__ Vb,
    unsigned short* __restrict__ qkv,
    const int* __restrict__ dst, int* __restrict__ counts8, int* __restrict__ rank)
{
    if (blockIdx.x < HIST_BLOCKS) {
        const int c = blockIdx.x & 7;
        int* cnt = counts8 + c * N_NODES;
        int tid = blockIdx.x * 256 + threadIdx.x;
        for (int e = tid; e < E_EDGES; e += HIST_BLOCKS * 256)
            rank[e] = atomicAdd(&cnt[dst[e]], 1);
        return;
    }

    __shared__ __align__(16) unsigned short smem[16384];   // 32 KB: W stage / output overlay
    const int t  = threadIdx.x;
    const int wv = t >> 6;
    const int l  = t & 63;
    const int lr = l & 15;       // A-row within tile / B-col within frag
    const int kg = l >> 4;       // k-group 0..3
    const int m_base = (blockIdx.x - HIST_BLOCKS) * 64 + wv * 16;
    const int arow = min(m_base + lr, N_NODES - 1);

    const float* pd = h_dst + (size_t)arow * IN_DIM;
    const float* ps = h_src + (size_t)arow * IN_DIM;

    // A fragments for h_dst (Q) and h_src (K,V): 16 float4 loads in flight
    short8v afd[4], afs[4];
    #pragma unroll
    for (int ks = 0; ks < 4; ++ks) {
        const int k0 = ks * 32 + kg * 8;
        float4 a0 = *(const float4*)&pd[k0];
        float4 a1 = *(const float4*)&pd[k0 + 4];
        float4 b0 = *(const float4*)&ps[k0];
        float4 b1 = *(const float4*)&ps[k0 + 4];
        afd[ks][0] = (short)f2bf(a0.x); afd[ks][1] = (short)f2bf(a0.y);
        afd[ks][2] = (short)f2bf(a0.z); afd[ks][3] = (short)f2bf(a0.w);
        afd[ks][4] = (short)f2bf(a1.x); afd[ks][5] = (short)f2bf(a1.y);
        afd[ks][6] = (short)f2bf(a1.z); afd[ks][7] = (short)f2bf(a1.w);
        afs[ks][0] = (short)f2bf(b0.x); afs[ks][1] = (short)f2bf(b0.y);
        afs[ks][2] = (short)f2bf(b0.z); afs[ks][3] = (short)f2bf(b0.w);
        afs[ks][4] = (short)f2bf(b1.x); afs[ks][5] = (short)f2bf(b1.y);
        afs[ks][6] = (short)f2bf(b1.z); afs[ks][7] = (short)f2bf(b1.w);
    }

    unsigned short* stg = &smem[wv * 4224];    // 2176 shorts used per wave (overlays W)

    #pragma unroll
    for (int phase = 0; phase < 3; ++phase) {
        if (phase) __syncthreads();            // everyone done with prev stage region
        // ---- cooperative W[phase] -> LDS, swizzled: byte d -> d ^ (((d>>8)&7)<<4) ----
        const unsigned short* wsrc = wt + ((size_t)phase << 14);
        #pragma unroll
        for (int j = 0; j < 8; ++j) {
            const int selem = j * 2048 + t * 8;              // short index, 16B chunks
            const int d = selem * 2;                         // linear byte addr
            const int sd = d ^ (((d >> 8) & 7) << 4);        // swizzled byte addr
            *(short8v*)((char*)smem + sd) = *(const short8v*)&wsrc[selem];
        }
        __syncthreads();

        // ---- MFMA: B-fragments from LDS ----
        const short8v* aF = (phase == 0) ? afd : afs;
        float4v acc[8];
        #pragma unroll
        for (int i = 0; i < 8; ++i) acc[i] = (float4v)0.f;
        #pragma unroll
        for (int ks = 0; ks < 4; ++ks) {
            #pragma unroll
            for (int nf = 0; nf < 8; ++nf) {
                const int a = (nf * 16 + lr) * 256 + ks * 64 + kg * 16;
                const int sa = a ^ ((lr & 7) << 4);
                short8v bf = *(const short8v*)((const char*)smem + sa);
                acc[nf] = __builtin_amdgcn_mfma_f32_16x16x32_bf16(aF[ks], bf, acc[nf], 0, 0, 0);
            }
        }
        __syncthreads();                       // all waves done reading W

        // ---- stage outputs (own region), then coalesced stores ----
        const float* bias = (phase == 0) ? Qb : (phase == 1) ? Kb : Vb;
        #pragma unroll
        for (int nf = 0; nf < 8; ++nf) {
            const float b = bias[nf * 16 + lr];
            #pragma unroll
            for (int r = 0; r < 4; ++r)
                stg[(kg * 4 + r) * 136 + nf * 16 + lr] = f2bf(acc[nf][r] + b);
        }
        #pragma unroll
        for (int i = 0; i < 4; ++i) {
            const int chunk = i * 64 + l;      // 256 chunks of 8 shorts = 16 rows x 128
            const int row = chunk >> 4;
            const int c   = (chunk & 15) * 8;
            const int m = m_base + row;
            short8v v = *(const short8v*)&stg[row * 136 + c];
            if (m < N_NODES) *(short8v*)&qkv[(size_t)m * 384 + phase * 128 + c] = v;
        }
    }
}

// ---------------- offsets: per-node 8-copy prefix + wave scan -> begn/cnt/begc ------
__global__ __launch_bounds__(256) void offsets_kernel(const int* __restrict__ counts8,
                                                      int* __restrict__ begc,
                                                      int* __restrict__ begn,
                                                      int* __restrict__ cntn,
                                                      int* __restrict__ total) {
    int n = blockIdx.x * blockDim.x + threadIdx.x;
    int lane = threadIdx.x & 63;
    int pre[8];
    int s = 0;
    if (n < N_NODES) {
        #pragma unroll
        for (int c = 0; c < 8; ++c) {          // coalesced per copy
            int v = counts8[c * N_NODES + n];
            pre[c] = s; s += v;
        }
    }
    int incl = s;
    #pragma unroll
    for (int off = 1; off < 64; off <<= 1) {
        int y = __shfl_up(incl, off);
        if (lane >= off) incl += y;
    }
    int wsum = __shfl(incl, 63);
    int base = 0;
    if (lane == 0) base = atomicAdd(total, wsum);
    base = __shfl(base, 0);
    int b = base + incl - s;
    if (n < N_NODES) {
        begn[n] = b; cntn[n] = s;
        #pragma unroll
        for (int c = 0; c < 8; ++c) begc[c * N_NODES + n] = b + pre[c];
    }
}

// ---------------- scatter: atomic-free via begc + rank ----------------
// edge e was histogrammed by block ((e mod 2^18) >> 8), so copy c = (e>>8)&7.
__global__ void scatter_kernel(const int* __restrict__ src, const int* __restrict__ dst,
                               const int* __restrict__ begc, const int* __restrict__ rank,
                               int* __restrict__ esrc) {
    int e = blockIdx.x * blockDim.x + threadIdx.x;
    if (e < E_EDGES) {
        int c = (e >> 8) & 7;
        esrc[begc[c * N_NODES + dst[e]] + rank[e]] = src[e];
    }
}

// ---------------- aggregation: one wave per node; lane = (e-slot 0..3, chunk u 0..15) ----
// 2x unrolled: 8 edges / iteration, 16 row-loads + 2 idx-loads in flight.
__global__ __launch_bounds__(256) void agg_kernel(
    const unsigned short* __restrict__ qkv,
    const int* __restrict__ begp, const int* __restrict__ cntp,
    const int* __restrict__ esrc, float* __restrict__ out)
{
    int wave = (blockIdx.x * blockDim.x + threadIdx.x) >> 6;
    const int lane = threadIdx.x & 63;
    if (wave >= N_NODES) return;
    const int n = __builtin_amdgcn_readfirstlane(wave);
    const int e = lane >> 4;
    const int u = lane & 15;

    const uint4 qv = *(const uint4*)&qkv[(size_t)n * 384 + u * 8];
    const float q0 = bflo(qv.x), q1 = bfhi(qv.x), q2 = bflo(qv.y), q3 = bfhi(qv.y);
    const float q4 = bflo(qv.z), q5 = bfhi(qv.z), q6 = bflo(qv.w), q7 = bfhi(qv.w);

    const int b0 = begp[n], c0 = cntp[n], endp = b0 + c0;

    float a0=0.f,a1=0.f,a2=0.f,a3=0.f,a4=0.f,a5=0.f,a6=0.f,a7=0.f, z=0.f;

    for (int base = b0; base < endp; base += 8) {
        const int i0 = base + e;
        const int i1 = base + 4 + e;
        const int s0 = esrc[min(i0, endp - 1)];
        const int s1 = esrc[min(i1, endp - 1)];
        const size_t r0 = (size_t)s0 * 384, r1 = (size_t)s1 * 384;
        const uint4 kk0 = *(const uint4*)&qkv[r0 + 128 + u * 8];
        const uint4 vv0 = *(const uint4*)&qkv[r0 + 256 + u * 8];
        const uint4 kk1 = *(const uint4*)&qkv[r1 + 128 + u * 8];
        const uint4 vv1 = *(const uint4*)&qkv[r1 + 256 + u * 8];

        float d0 =      q0 * bflo(kk0.x);
        d0 = fmaf(q1, bfhi(kk0.x), d0);
        d0 = fmaf(q2, bflo(kk0.y), d0);
        d0 = fmaf(q3, bfhi(kk0.y), d0);
        d0 = fmaf(q4, bflo(kk0.z), d0);
        d0 = fmaf(q5, bfhi(kk0.z), d0);
        d0 = fmaf(q6, bflo(kk0.w), d0);
        d0 = fmaf(q7, bfhi(kk0.w), d0);
        d0 += __shfl_xor(d0, 1);
        float w0 = (i0 < endp) ? __expf(fminf(fmaxf(d0 * SQRT_D_INV, -5.f), 5.f)) : 0.f;
        z += w0;
        a0 = fmaf(w0, bflo(vv0.x), a0);
        a1 = fmaf(w0, bfhi(vv0.x), a1);
        a2 = fmaf(w0, bflo(vv0.y), a2);
        a3 = fmaf(w0, bfhi(vv0.y), a3);
        a4 = fmaf(w0, bflo(vv0.z), a4);
        a5 = fmaf(w0, bfhi(vv0.z), a5);
        a6 = fmaf(w0, bflo(vv0.w), a6);
        a7 = fmaf(w0, bfhi(vv0.w), a7);

        float d1 =      q0 * bflo(kk1.x);
        d1 = fmaf(q1, bfhi(kk1.x), d1);
        d1 = fmaf(q2, bflo(kk1.y), d1);
        d1 = fmaf(q3, bfhi(kk1.y), d1);
        d1 = fmaf(q4, bflo(kk1.z), d1);
        d1 = fmaf(q5, bfhi(kk1.z), d1);
        d1 = fmaf(q6, bflo(kk1.w), d1);
        d1 = fmaf(q7, bfhi(kk1.w), d1);
        d1 += __shfl_xor(d1, 1);
        float w1 = (i1 < endp) ? __expf(fminf(fmaxf(d1 * SQRT_D_INV, -5.f), 5.f)) : 0.f;
        z += w1;
        a0 = fmaf(w1, bflo(vv1.x), a0);
        a1 = fmaf(w1, bfhi(vv1.x), a1);
        a2 = fmaf(w1, bflo(vv1.y), a2);
        a3 = fmaf(w1, bfhi(vv1.y), a3);
        a4 = fmaf(w1, bflo(vv1.z), a4);
        a5 = fmaf(w1, bfhi(vv1.z), a5);
        a6 = fmaf(w1, bflo(vv1.w), a6);
        a7 = fmaf(w1, bfhi(vv1.w), a7);
    }

    #pragma unroll
    for (int mask = 16; mask <= 32; mask <<= 1) {
        z  += __shfl_xor(z, mask);
        a0 += __shfl_xor(a0, mask);
        a1 += __shfl_xor(a1, mask);
        a2 += __shfl_xor(a2, mask);
        a3 += __shfl_xor(a3, mask);
        a4 += __shfl_xor(a4, mask);
        a5 += __shfl_xor(a5, mask);
        a6 += __shfl_xor(a6, mask);
        a7 += __shfl_xor(a7, mask);
    }

    const float inv = 1.f / z;     // deg==0 -> 0*inf = NaN, matching reference 0/0
    if (e == 0) {
        *(float4*)&out[(size_t)n * HD + u * 8]     = make_float4(a0*inv, a1*inv, a2*inv, a3*inv);
        *(float4*)&out[(size_t)n * HD + u * 8 + 4] = make_float4(a4*inv, a5*inv, a6*inv, a7*inv);
    }
}

// ---------------- launcher ----------------
extern "C" void kernel_launch(void* const* d_in, const int* in_sizes, int n_in,
                              void* d_out, int out_size, void* d_ws, size_t ws_size,
                              hipStream_t stream) {
    const float* h_src = (const float*)d_in[0];
    const float* h_dst = (const float*)d_in[1];
    const int*   src   = (const int*)d_in[2];
    const int*   dst   = (const int*)d_in[3];
    const float* Qw    = (const float*)d_in[4];
    const float* Qb    = (const float*)d_in[5];
    const float* Kw    = (const float*)d_in[6];
    const float* Kb    = (const float*)d_in[7];
    const float* Vw    = (const float*)d_in[8];
    const float* Vb    = (const float*)d_in[9];
    float* out = (float*)d_out;

    char* ws = (char*)d_ws;
    const size_t qkv_bytes = (size_t)N_NODES * 384 * sizeof(unsigned short);  // 38.4 MB
    const size_t wt_bytes  = 3 * 128 * 128 * sizeof(unsigned short);          // 96 KB
    unsigned short* qkvp = (unsigned short*)(ws);
    unsigned short* wtp  = (unsigned short*)(ws + qkv_bytes);
    int* counts8 = (int*)(ws + qkv_bytes + wt_bytes);   // 8*N + 1 (total at [8N])
    int* total   = counts8 + 8 * N_NODES;
    int* begc    = counts8 + 8 * N_NODES + 1;           // 8*N
    int* begn    = begc + 8 * N_NODES;                  // N
    int* cntn    = begn + N_NODES;                      // N
    int* rank    = cntn + N_NODES;                      // E
    int* esrc    = rank + E_EDGES;                      // E

    wtr_init_kernel<<<392, 256, 0, stream>>>(Qw, Kw, Vw, wtp, counts8);

    proj_hist_kernel<<<HIST_BLOCKS + PROJ_BLOCKS, 256, 0, stream>>>(
        h_src, h_dst, wtp, Qb, Kb, Vb, qkvp, dst, counts8, rank);

    offsets_kernel<<<(N_NODES + 255) / 256, 256, 0, stream>>>(counts8, begc, begn, cntn, total);

    scatter_kernel<<<(E_EDGES + 255) / 256, 256, 0, stream>>>(src, dst, begc, rank, esrc);

    agg_kernel<<<(N_NODES * 64 + 255) / 256, 256, 0, stream>>>(qkvp, begn, cntn, esrc, out);
}